// Round 11
// baseline (559.862 us; speedup 1.0000x reference)
//
#include <hip/hip_runtime.h>

typedef unsigned short u16;
typedef __attribute__((ext_vector_type(8))) short bf16x8;
typedef __attribute__((ext_vector_type(4))) float f32x4;
#define EPSV 1e-5f
#define LOG2E 1.4426950408889634f

__device__ __forceinline__ float b2f(u16 u) {
  union { float f; unsigned int i; } v; v.i = ((unsigned int)u) << 16; return v.f;
}
__device__ __forceinline__ u16 f2b(float f) {
  union { float f; unsigned int i; } v; v.f = f;
  unsigned int r = v.i + 0x7FFFu + ((v.i >> 16) & 1u);
  return (u16)(r >> 16);
}
__device__ __forceinline__ u16 f2b_trunc(float f) {
  union { float f; unsigned int i; } v; v.f = f;
  return (u16)(v.i >> 16);
}
__device__ __forceinline__ float silu_(float z) { return z / (1.f + exp2f(-LOG2E * z)); }

// ---------------- dtype detect ----------------
__global__ __launch_bounds__(128) void detect_k(const u16* __restrict__ xp, float* __restrict__ flag) {
  __shared__ int cnt[2];
  int t = threadIdx.x;
  if (t < 2) cnt[t] = 0;
  __syncthreads();
  u16 u = xp[t * 2];
  int e = (u >> 7) & 0xff;
  if (e != 0 && (e < 90 || e > 160)) atomicAdd(&cnt[0], 1);
  if (u == 0) atomicAdd(&cnt[1], 1);
  __syncthreads();
  if (t == 0) *flag = (cnt[0] > 16 || cnt[1] > 64) ? 1.f : 0.f;
}

// ---------------- input conversion ----------------

struct ConvArgs {
  const void* src[30];
  long dst[30];
  int end[30];
  int mode[30];
};

__global__ __launch_bounds__(256) void convert_all(ConvArgs a, float* __restrict__ wsF,
                                                   u16* __restrict__ wsH,
                                                   const float* __restrict__ flagp, int total) {
  const int flag = (*flagp > 0.5f);
  int gid = blockIdx.x * 256 + threadIdx.x;
  if (gid >= total) return;
  #pragma unroll 1
  for (int s = 0; s < 30; ++s) {
    if (gid < a.end[s]) {
      int idx = gid - (s ? a.end[s - 1] : 0);
      if (a.mode[s] == 0) {
        float v = flag ? ((const float*)a.src[s])[idx] : b2f(((const u16*)a.src[s])[idx]);
        wsF[a.dst[s] + idx] = v;
      } else {
        u16 h = flag ? f2b(((const float*)a.src[s])[idx]) : ((const u16*)a.src[s])[idx];
        wsH[a.dst[s] + idx] = h;
      }
      return;
    }
  }
}

// conv3 weight transform: fp32 W[o][I][3][3] -> bf16 Wt[I/32][tap][256o][32ch]
__global__ __launch_bounds__(256) void w3t(const float* __restrict__ Wsrc, u16* __restrict__ Wdst) {
  int idx = blockIdx.x * 256 + threadIdx.x;
  int ch = idx & 31;
  int o  = (idx >> 5) & 255;
  int tap = (idx >> 13) % 9;
  int c8 = (idx >> 13) / 9;
  int i = c8 * 32 + ch;
  Wdst[idx] = f2b(Wsrc[((long)o * 256 + i) * 9 + tap]);
}

// fp32 -> bf16 bulk convert (8 elems/thread)
__global__ __launch_bounds__(256) void cvtb(const float* __restrict__ src, u16* __restrict__ dst, int n8) {
  int i = blockIdx.x * 256 + threadIdx.x;
  if (i >= n8) return;
  float4 f0 = *(const float4*)(src + (long)i * 8);
  float4 f1 = *(const float4*)(src + (long)i * 8 + 4);
  union { u16 h[8]; uint4 q; } u;
  u.h[0]=f2b(f0.x); u.h[1]=f2b(f0.y); u.h[2]=f2b(f0.z); u.h[3]=f2b(f0.w);
  u.h[4]=f2b(f1.x); u.h[5]=f2b(f1.y); u.h[6]=f2b(f1.z); u.h[7]=f2b(f1.w);
  *(uint4*)(dst + (long)i * 8) = u.q;
}

// ---------------- CoordAtt ----------------

__global__ __launch_bounds__(256) void plane_means(const float* __restrict__ x, float* __restrict__ yin) {
  __shared__ float pl[4096];
  int bc = blockIdx.x, t = threadIdx.x;
  const float* xp = x + (long)bc * 4096;
  for (int j = 0; j < 16; ++j) { int id = j * 256 + t; pl[id] = xp[id]; }
  __syncthreads();
  if (t < 64) {
    float s = 0.f;
    for (int w = 0; w < 64; ++w) s += pl[t * 64 + w];
    yin[(long)bc * 128 + t] = s * (1.f / 64.f);
  } else if (t < 128) {
    int w = t - 64; float s = 0.f;
    for (int h = 0; h < 64; ++h) s += pl[h * 64 + w];
    yin[(long)bc * 128 + 64 + w] = s * (1.f / 64.f);
  }
}

__global__ __launch_bounds__(128) void ca_conv1(const float* __restrict__ yin, const float* __restrict__ w1,
                                                const float* __restrict__ b1, const float* __restrict__ bnp,
                                                float* __restrict__ ybn) {
  int b = blockIdx.x, p = threadIdx.x;
  float acc[8] = {0.f,0.f,0.f,0.f,0.f,0.f,0.f,0.f};
  for (int c = 0; c < 256; ++c) {
    float yv = yin[((long)b * 256 + c) * 128 + p];
    #pragma unroll
    for (int o = 0; o < 8; ++o) acc[o] += w1[o * 256 + c] * yv;
  }
  #pragma unroll
  for (int o = 0; o < 8; ++o) {
    float z = acc[o] + b1[o];
    float g = bnp[o], bt = bnp[8 + o], mn = bnp[16 + o], vr = bnp[24 + o];
    float s = g * rsqrtf(vr + EPSV);
    z = z * s + (bt - mn * s);
    float hs = fminf(fmaxf(z + 3.f, 0.f), 6.f) * (1.f / 6.f);
    ybn[((long)b * 8 + o) * 128 + p] = z * hs;
  }
}

__global__ __launch_bounds__(128) void ca_gate(const float* __restrict__ ybn,
    const float* __restrict__ wh, const float* __restrict__ bh,
    const float* __restrict__ ww, const float* __restrict__ bw,
    float* __restrict__ ah, float* __restrict__ aw_) {
  int c = blockIdx.x, b = blockIdx.y, t = threadIdx.x;
  if (t < 64) {
    float d = 0.f;
    #pragma unroll
    for (int o = 0; o < 8; ++o) d += wh[c * 8 + o] * ybn[((long)b * 8 + o) * 128 + t];
    d += bh[c];
    ah[((long)b * 256 + c) * 64 + t] = 1.f / (1.f + exp2f(-LOG2E * d));
  } else {
    int w = t - 64;
    float d = 0.f;
    #pragma unroll
    for (int o = 0; o < 8; ++o) d += ww[c * 8 + o] * ybn[((long)b * 8 + o) * 128 + 64 + w];
    d += bw[c];
    aw_[((long)b * 256 + c) * 64 + w] = 1.f / (1.f + exp2f(-LOG2E * d));
  }
}

// r (bf16 out) = x * a_h * a_w
__global__ __launch_bounds__(256) void apply_ca(const float* __restrict__ x, const float* __restrict__ ah,
                                                const float* __restrict__ aw_, u16* __restrict__ r) {
  int idx = blockIdx.x * 256 + threadIdx.x;
  int n = idx & 4095, bc = idx >> 12;
  int h = n >> 6, w = n & 63;
  r[idx] = f2b(x[idx] * ah[bc * 64 + h] * aw_[bc * 64 + w]);
}

// ---------------- MFMA 1x1 conv, 64o x 64n tile (2 blocks/CU): bf16 in; OUTH -> bf16/fp32 out ----------------

template<int ACT, int OUTH>
__global__ __launch_bounds__(256) void mfma_cbs(
    const u16* __restrict__ Wbf, long aBS,
    const u16* __restrict__ In, long bBS,
    void* __restrict__ Out, long oBS,
    int O, int K, int N,
    const float* __restrict__ bnp, const float* __restrict__ bias)
{
  __shared__ u16 As[64 * 40];
  __shared__ u16 Bs[64 * 40];
  __shared__ float albe[64][2];
  const int t = threadIdx.x;
  const int n0 = blockIdx.x * 64;
  const int o0 = blockIdx.y * 64;
  const int b  = blockIdx.z;
  const int w = t >> 6, l = t & 63, lq = l >> 4, lr = l & 15;
  const int wo = (w >> 1) * 32, wn = (w & 1) * 32;
  if (t < 64) {
    int o = o0 + t;
    float al = 1.f, be = 0.f;
    if (bnp) {
      float g = bnp[o], bt = bnp[O + o], mn = bnp[2 * O + o], vr = bnp[3 * O + o];
      al = g * rsqrtf(vr + EPSV); be = bt - mn * al;
    }
    if (bias) be += bias[o];
    albe[t][0] = al; albe[t][1] = be;
  }
  const u16* Ab = Wbf + (long)b * aBS;
  const u16* inb = In + (long)b * bBS + n0;
  const int ao = t >> 2, akq = (t & 3) * 8;       // A: 64o x 32k, uint4/thread
  const int bk = t >> 3, bn8 = (t & 7) * 8;       // B: 32k x 64n, uint4/thread
  f32x4 acc[2][2] = {};
  for (int kc = 0; kc < K; kc += 32) {
    __syncthreads();
    *(uint4*)&As[ao * 40 + akq] = *(const uint4*)(Ab + (long)(o0 + ao) * K + kc + akq);
    union { uint4 q; u16 h[8]; } tb;
    tb.q = *(const uint4*)(inb + (long)(kc + bk) * N + bn8);
    #pragma unroll
    for (int j = 0; j < 8; ++j) Bs[(bn8 + j) * 40 + bk] = tb.h[j];
    __syncthreads();
    bf16x8 af[2], bfv[2];
    #pragma unroll
    for (int i = 0; i < 2; ++i) af[i] = *(const bf16x8*)&As[(wo + i * 16 + lr) * 40 + lq * 8];
    #pragma unroll
    for (int j = 0; j < 2; ++j) bfv[j] = *(const bf16x8*)&Bs[(wn + j * 16 + lr) * 40 + lq * 8];
    #pragma unroll
    for (int i = 0; i < 2; ++i)
      #pragma unroll
      for (int j = 0; j < 2; ++j)
        acc[i][j] = __builtin_amdgcn_mfma_f32_16x16x32_bf16(af[i], bfv[j], acc[i][j], 0, 0, 0);
  }
  float* ob = (float*)Out + (long)b * oBS;
  u16* obh = (u16*)Out + (long)b * oBS;
  #pragma unroll
  for (int i = 0; i < 2; ++i) {
    #pragma unroll
    for (int r = 0; r < 4; ++r) {
      int ol = wo + i * 16 + lq * 4 + r;
      float al = albe[ol][0], be = albe[ol][1];
      #pragma unroll
      for (int j = 0; j < 2; ++j) {
        float vv = acc[i][j][r] * al + be;
        if (ACT) vv = silu_(vv);
        if (OUTH) obh[(long)(o0 + ol) * N + n0 + wn + j * 16 + lr] = f2b(vv);
        else      ob[(long)(o0 + ol) * N + n0 + wn + j * 16 + lr] = vv;
      }
    }
  }
}

// ---------------- MFMA 3x3 conv (implicit GEMM), bf16 in/out ----------------
__global__ __launch_bounds__(256) void conv3_mfma(
    const u16* __restrict__ Wt,
    const u16* __restrict__ In, long iBS,
    u16* __restrict__ Out, long oBS, int O, int I,
    const float* __restrict__ bnp)
{
  __shared__ u16 As[9 * 64 * 34];
  __shared__ u16 Bs[4 * 66 * 34];
  __shared__ float albe[64][2];
  const int t = threadIdx.x;
  const int h0 = blockIdx.x * 2;
  const int o0 = blockIdx.y * 64;
  const int b  = blockIdx.z;
  const int w = t >> 6, l = t & 63, lq = l >> 4, lr = l & 15;
  const int wo = (w >> 1) * 32, wn = (w & 1) * 64;
  if (t < 64) {
    int o = o0 + t;
    float g = bnp[o], bt = bnp[O + o], mn = bnp[2 * O + o], vr = bnp[3 * O + o];
    float al = g * rsqrtf(vr + EPSV);
    albe[t][0] = al; albe[t][1] = bt - mn * al;
  }
  {
    int r = t >> 6, cs = (t >> 5) & 1, ch = t & 31;
    Bs[(r * 66 + (cs ? 65 : 0)) * 34 + ch] = 0;
  }
  const u16* inb = In + (long)b * iBS;
  const int bch = t >> 3, bcg = (t & 7) * 8;
  f32x4 acc[2][4] = {};
  for (int c8 = 0; c8 < (I >> 5); ++c8) {
    __syncthreads();
    {
      const u16* wsrc = Wt + (long)c8 * 9 * 256 * 32;
      #pragma unroll
      for (int j = 0; j < 9; ++j) {
        int e = j * 2048 + t * 8;
        int tap = e >> 11, o = (e >> 5) & 63, ch0 = e & 31;
        uint4 vv = *(const uint4*)(wsrc + ((long)tap * 256 + o0 + o) * 32 + ch0);
        *(uint4*)&As[(tap * 64 + o) * 34 + ch0] = vv;
      }
    }
    {
      const u16* cbase = inb + (long)(c8 * 32 + bch) * 4096;
      #pragma unroll
      for (int r = 0; r < 4; ++r) {
        int row = h0 - 1 + r;
        union { uint4 q; u16 h[8]; } tb;
        if (row >= 0 && row < 64) {
          tb.q = *(const uint4*)(cbase + row * 64 + bcg);
        } else {
          tb.q = make_uint4(0, 0, 0, 0);
        }
        #pragma unroll
        for (int j2 = 0; j2 < 8; ++j2)
          Bs[(r * 66 + bcg + 1 + j2) * 34 + bch] = tb.h[j2];
      }
    }
    __syncthreads();
    #pragma unroll
    for (int dy = 0; dy < 3; ++dy) {
      #pragma unroll
      for (int dx = 0; dx < 3; ++dx) {
        const int tap = dy * 3 + dx;
        bf16x8 af0 = *(const bf16x8*)&As[(tap * 64 + wo + lr) * 34 + lq * 8];
        bf16x8 af1 = *(const bf16x8*)&As[(tap * 64 + wo + 16 + lr) * 34 + lq * 8];
        #pragma unroll
        for (int j = 0; j < 4; ++j) {
          int nb = wn + j * 16;
          int rowS = (nb >> 6) + dy;
          int colS = (nb & 63) + dx;
          bf16x8 bv = *(const bf16x8*)&Bs[(rowS * 66 + colS + lr) * 34 + lq * 8];
          acc[0][j] = __builtin_amdgcn_mfma_f32_16x16x32_bf16(af0, bv, acc[0][j], 0, 0, 0);
          acc[1][j] = __builtin_amdgcn_mfma_f32_16x16x32_bf16(af1, bv, acc[1][j], 0, 0, 0);
        }
      }
    }
  }
  u16* ob = Out + (long)b * oBS;
  const int n0 = h0 * 64;
  #pragma unroll
  for (int i = 0; i < 2; ++i) {
    #pragma unroll
    for (int r = 0; r < 4; ++r) {
      int ol = wo + i * 16 + lq * 4 + r;
      float al = albe[ol][0], be = albe[ol][1];
      #pragma unroll
      for (int j = 0; j < 4; ++j) {
        float vv = silu_(acc[i][j][r] * al + be);
        ob[(long)(o0 + ol) * 4096 + n0 + wn + j * 16 + lr] = f2b(vv);
      }
    }
  }
}

// ---------------- fused chained maxpools: x1 -> mp5 -> mp9 -> mp13 (bf16, in-LDS) ----------------
// grid (256 c, B). cat sections: s*CNu within batch (batch stride bs u16).
__global__ __launch_bounds__(256) void pool3(u16* __restrict__ cat, long bs) {
  __shared__ float A[68][72];
  __shared__ float Bb[68][72];
  const int t = threadIdx.x;
  const int c = blockIdx.x, b = blockIdx.y;
  u16* base = cat + (long)b * bs + (long)c * 4096;
  for (int i = t; i < 68 * 72; i += 256) { (&A[0][0])[i] = -1e30f; (&Bb[0][0])[i] = -1e30f; }
  __syncthreads();
  const int r = t >> 2, c0 = (t & 3) * 16;
  #pragma unroll
  for (int j = 0; j < 16; ++j) A[r + 2][c0 + 2 + j] = b2f(base[r * 64 + c0 + j]);
  const long CNu = 1048576;
  #pragma unroll 1
  for (int s = 1; s <= 3; ++s) {
    __syncthreads();
    #pragma unroll
    for (int j = 0; j < 16; ++j) {
      int cc = c0 + j;   // image col; halo col = cc+2; window halo cols cc..cc+4
      float m = fmaxf(fmaxf(fmaxf(A[r+2][cc], A[r+2][cc+1]), fmaxf(A[r+2][cc+2], A[r+2][cc+3])), A[r+2][cc+4]);
      Bb[r + 2][cc + 2] = m;
    }
    __syncthreads();
    u16* out = base + (long)s * CNu;
    #pragma unroll
    for (int j = 0; j < 16; ++j) {
      int hc = c0 + 2 + j;  // halo col; window halo rows r..r+4
      float m = fmaxf(fmaxf(fmaxf(Bb[r][hc], Bb[r+1][hc]), fmaxf(Bb[r+2][hc], Bb[r+3][hc])), Bb[r+4][hc]);
      out[r * 64 + c0 + j] = f2b_trunc(m);
      A[r + 2][hc] = m;
    }
  }
}

// ---------------- bf16 transpose: (B,64,4096) -> (B,4096,64) ----------------
__global__ __launch_bounds__(256) void transpose_hh(const u16* __restrict__ in, u16* __restrict__ out) {
  __shared__ u16 tile[32][34];
  int b = blockIdx.z;
  int c0 = blockIdx.x * 32, r0 = blockIdx.y * 32;
  int tx = threadIdx.x & 31, ty = threadIdx.x >> 5;
  const u16* ib = in + (long)b * 262144;
  u16* ob = out + (long)b * 262144;
  #pragma unroll
  for (int i = 0; i < 4; ++i) {
    int r = r0 + ty + i * 8;
    tile[ty + i * 8][tx] = ib[(long)r * 4096 + c0 + tx];
  }
  __syncthreads();
  #pragma unroll
  for (int i = 0; i < 4; ++i) {
    int c = c0 + ty + i * 8;
    ob[(long)c * 64 + r0 + tx] = tile[tx][ty + i * 8];
  }
}

// ---------------- PAM row-max via MFMA (qkT: [b][4096][64]), K-prefetch ----------------
__global__ __launch_bounds__(256) void pam_qk_max(const u16* __restrict__ qkT, float* __restrict__ pmax) {
  __shared__ u16 Qs[32 * 40];
  __shared__ u16 Ks[64 * 40];
  __shared__ float red[4][32][17];
  const int t = threadIdx.x;
  const int b = blockIdx.z, ms = blockIdx.y, n0 = blockIdx.x * 32;
  const int w = t >> 6, l = t & 63, lq = l >> 4, lr = l & 15;
  const int wn = w & 1, wc = w >> 1;
  if (t < 128) {
    int row = t >> 2, cq = (t & 3) * 8;
    *(uint4*)&Qs[row * 40 + cq] = *(const uint4*)(qkT + ((long)b * 4096 + n0 + row) * 64 + cq);
  }
  __syncthreads();
  bf16x8 qf = *(const bf16x8*)&Qs[(wn * 16 + lr) * 40 + lq * 8];
  float mx4[4] = {-1e30f, -1e30f, -1e30f, -1e30f};
  const int krow = t >> 2, kcq = (t & 3) * 8;
  const u16* kb = qkT + ((long)b * 4096 + ms * 1024 + krow) * 64 + 32 + kcq;
  uint4 kpre = *(const uint4*)kb;
  for (int it = 0; it < 16; ++it) {
    __syncthreads();
    *(uint4*)&Ks[krow * 40 + kcq] = kpre;
    __syncthreads();
    if (it < 15) kpre = *(const uint4*)(kb + (long)(it + 1) * 64 * 64);
    #pragma unroll
    for (int s = 0; s < 2; ++s) {
      int msub = wc * 2 + s;
      bf16x8 kf = *(const bf16x8*)&Ks[(msub * 16 + lr) * 40 + lq * 8];
      f32x4 S = {};
      S = __builtin_amdgcn_mfma_f32_16x16x32_bf16(qf, kf, S, 0, 0, 0);
      #pragma unroll
      for (int r = 0; r < 4; ++r) mx4[r] = fmaxf(mx4[r], S[r]);
    }
  }
  #pragma unroll
  for (int r = 0; r < 4; ++r) red[w][wn * 16 + lq * 4 + r][lr] = mx4[r];
  __syncthreads();
  if (t < 32) {
    int wbase = t >> 4;
    float M = -1e30f;
    #pragma unroll
    for (int j = 0; j < 2; ++j)
      #pragma unroll
      for (int l2 = 0; l2 < 16; ++l2)
        M = fmaxf(M, red[wbase + 2 * j][t][l2]);
    pmax[((long)ms * 2 + b) * 4096 + n0 + t] = M;
  }
}

__global__ __launch_bounds__(256) void pam_merge(const float* __restrict__ pmax, float* __restrict__ rmx) {
  int i = blockIdx.x * 256 + threadIdx.x;
  int b = i >> 12, n = i & 4095;
  float m = pmax[(long)b * 4096 + n];
  #pragma unroll
  for (int ms = 1; ms < 4; ++ms) m = fmaxf(m, pmax[((long)ms * 2 + b) * 4096 + n]);
  rmx[i] = m;
}

// ---------------- PAM attention: m-split x2, K/V register prefetch, un-normalized partials ----------------
__global__ __launch_bounds__(512) void pam_attn(const u16* __restrict__ qkT,
    const u16* __restrict__ vb, const float* __restrict__ rowmax,
    float* __restrict__ Obase, float* __restrict__ Sbase) {
  __shared__ u16 Qs[32 * 40];
  __shared__ u16 Ks[64 * 40];
  __shared__ u16 Vs[256 * 72];
  __shared__ u16 Ps[32 * 72];
  __shared__ float rmL[32];
  __shared__ float srow[32];
  const int t = threadIdx.x;
  const int mh = blockIdx.y;
  const int b = blockIdx.z;
  const int n0 = blockIdx.x * 32;
  const int w = t >> 6, l = t & 63, lq = l >> 4, lr = l & 15;
  const int nf = w & 1;
  const int mf = w >> 1;
  const int cw = w * 32;
  float* O = Obase + (long)mh * 2097152;
  float* S = Sbase + (long)mh * 8192;
  if (t < 128) {
    int row = t >> 2, cq = (t & 3) * 8;
    *(uint4*)&Qs[row * 40 + cq] = *(const uint4*)(qkT + ((long)b * 4096 + n0 + row) * 64 + cq);
  }
  if (t < 32) { rmL[t] = rowmax[(long)b * 4096 + n0 + t] * LOG2E; srow[t] = 0.f; }
  __syncthreads();
  bf16x8 qf = *(const bf16x8*)&Qs[(nf * 16 + lr) * 40 + lq * 8];
  float rm4[4];
  #pragma unroll
  for (int r = 0; r < 4; ++r) rm4[r] = rmL[nf * 16 + lq * 4 + r];
  float sp[4] = {0.f, 0.f, 0.f, 0.f};
  f32x4 acc[2][2] = {};
  const int krow = t >> 3, kc4 = (t & 7) * 4;
  const int vcc = t >> 1, vm = (t & 1) * 32;
  const u16* kbase = qkT + ((long)b * 4096 + krow) * 64 + 32 + kc4;
  const u16* vbase = vb + ((long)b * 256 + vcc) * 4096 + vm;
  const int mStart = mh * 2048, mEnd = mStart + 2048;
  uint2 kpre;
  uint4 vpre[4];
  {
    kpre = *(const uint2*)(kbase + (long)mStart * 64);
    const u16* src = vbase + mStart;
    #pragma unroll
    for (int i = 0; i < 4; ++i) vpre[i] = *(const uint4*)(src + i * 8);
  }
  for (int m0 = mStart; m0 < mEnd; m0 += 64) {
    __syncthreads();
    *(uint2*)&Ks[krow * 40 + kc4] = kpre;
    {
      u16* dst = &Vs[vcc * 72 + vm];
      #pragma unroll
      for (int i = 0; i < 4; ++i) *(uint4*)(dst + i * 8) = vpre[i];
    }
    __syncthreads();
    if (m0 + 64 < mEnd) {
      kpre = *(const uint2*)(kbase + (long)(m0 + 64) * 64);
      const u16* src = vbase + m0 + 64;
      #pragma unroll
      for (int i = 0; i < 4; ++i) vpre[i] = *(const uint4*)(src + i * 8);
    }
    {
      bf16x8 kf = *(const bf16x8*)&Ks[(mf * 16 + lr) * 40 + lq * 8];
      f32x4 Sv = {};
      Sv = __builtin_amdgcn_mfma_f32_16x16x32_bf16(qf, kf, Sv, 0, 0, 0);
      #pragma unroll
      for (int r = 0; r < 4; ++r) {
        float p = exp2f(Sv[r] * LOG2E - rm4[r]);
        sp[r] += p;
        Ps[(nf * 16 + lq * 4 + r) * 72 + mf * 16 + lr] = f2b_trunc(p);
      }
    }
    __syncthreads();
    #pragma unroll
    for (int ks = 0; ks < 2; ++ks) {
      bf16x8 pf0 = *(const bf16x8*)&Ps[lr * 72 + ks * 32 + lq * 8];
      bf16x8 pf1 = *(const bf16x8*)&Ps[(16 + lr) * 72 + ks * 32 + lq * 8];
      #pragma unroll
      for (int cf = 0; cf < 2; ++cf) {
        bf16x8 vf = *(const bf16x8*)&Vs[(cw + cf * 16 + lr) * 72 + ks * 32 + lq * 8];
        acc[cf][0] = __builtin_amdgcn_mfma_f32_16x16x32_bf16(vf, pf0, acc[cf][0], 0, 0, 0);
        acc[cf][1] = __builtin_amdgcn_mfma_f32_16x16x32_bf16(vf, pf1, acc[cf][1], 0, 0, 0);
      }
    }
  }
  #pragma unroll
  for (int r = 0; r < 4; ++r) {
    float s = sp[r];
    s += __shfl_xor(s, 1); s += __shfl_xor(s, 2);
    s += __shfl_xor(s, 4); s += __shfl_xor(s, 8);
    if (lr == 0) atomicAdd(&srow[nf * 16 + lq * 4 + r], s);
  }
  __syncthreads();
  if (t < 32) S[(long)b * 4096 + n0 + t] = srow[t];
  float* ob = O + (long)b * 1048576 + n0;
  #pragma unroll
  for (int cf = 0; cf < 2; ++cf) {
    #pragma unroll
    for (int r = 0; r < 4; ++r) {
      int c = cw + cf * 16 + lq * 4 + r;
      ob[(long)c * 4096 + lr]      = acc[cf][0][r];
      ob[(long)c * 4096 + 16 + lr] = acc[cf][1][r];
    }
  }
}

// ---------------- CAM ----------------

__global__ __launch_bounds__(256) void fillz(float* __restrict__ p, int n) {
  int i = blockIdx.x * 256 + threadIdx.x;
  if (i < n) p[i] = 0.f;
}

// e[b,c,d] += sum over this block's K slice (split-K x16)
__global__ __launch_bounds__(256) void cam_e_mfma(const u16* __restrict__ resb, float* __restrict__ e) {
  __shared__ u16 As[64 * 40];
  __shared__ u16 Bs[128 * 40];
  const int t = threadIdx.x;
  const int d0 = blockIdx.x * 128;
  const int c0 = blockIdx.y * 64;
  const int bz = blockIdx.z;
  const int b = bz >> 4, ks = bz & 15;
  const int w = t >> 6, l = t & 63, lq = l >> 4, lr = l & 15;
  const int wo = (w >> 1) * 32, wn = (w & 1) * 64;
  const u16* fb = resb + (long)b * 1048576;
  const int ao = t >> 2, akq = (t & 3) * 8;
  const int bo = t >> 1, bkq = (t & 1) * 16;
  f32x4 acc[2][4] = {};
  for (int kc = ks * 256; kc < ks * 256 + 256; kc += 32) {
    __syncthreads();
    *(uint4*)&As[ao * 40 + akq] = *(const uint4*)(fb + (long)(c0 + ao) * 4096 + kc + akq);
    #pragma unroll
    for (int i = 0; i < 2; ++i)
      *(uint4*)&Bs[bo * 40 + bkq + i * 8] = *(const uint4*)(fb + (long)(d0 + bo) * 4096 + kc + bkq + i * 8);
    __syncthreads();
    bf16x8 af[2], bfv[4];
    #pragma unroll
    for (int i = 0; i < 2; ++i) af[i] = *(const bf16x8*)&As[(wo + i * 16 + lr) * 40 + lq * 8];
    #pragma unroll
    for (int j = 0; j < 4; ++j) bfv[j] = *(const bf16x8*)&Bs[(wn + j * 16 + lr) * 40 + lq * 8];
    #pragma unroll
    for (int i = 0; i < 2; ++i)
      #pragma unroll
      for (int j = 0; j < 4; ++j)
        acc[i][j] = __builtin_amdgcn_mfma_f32_16x16x32_bf16(af[i], bfv[j], acc[i][j], 0, 0, 0);
  }
  #pragma unroll
  for (int i = 0; i < 2; ++i)
    #pragma unroll
    for (int r = 0; r < 4; ++r) {
      int ol = wo + i * 16 + lq * 4 + r;
      #pragma unroll
      for (int j = 0; j < 4; ++j)
        atomicAdd(&e[((long)b << 16) + (long)(c0 + ol) * 256 + d0 + wn + j * 16 + lr], acc[i][j][r]);
    }
}

__global__ __launch_bounds__(256) void cam_softmax(const float* __restrict__ e, u16* __restrict__ attn) {
  __shared__ float red[256];
  int c = blockIdx.x, b = blockIdx.y, t = threadIdx.x;
  const float* row = e + ((long)b << 16) + (long)c * 256;
  float v = row[t];
  red[t] = v; __syncthreads();
  for (int s = 128; s > 0; s >>= 1) { if (t < s) red[t] = fminf(red[t], red[t + s]); __syncthreads(); }
  float emin = red[0]; __syncthreads();
  float ex = exp2f(LOG2E * (emin - v));
  red[t] = ex; __syncthreads();
  for (int s = 128; s > 0; s >>= 1) { if (t < s) red[t] += red[t + s]; __syncthreads(); }
  float inv = 1.f / red[0];
  attn[((long)b << 16) + (long)c * 256 + t] = f2b(ex * inv);
}

// ---------------- final combine (fuses PAM partial merge) ----------------

__global__ __launch_bounds__(256) void combine(const float* __restrict__ res, const float* __restrict__ O,
    const float* __restrict__ S, const float* __restrict__ cam, const float* __restrict__ gp,
    void* __restrict__ outp, const float* __restrict__ flagp) {
  int idx = blockIdx.x * 256 + threadIdx.x;
  int b = idx >> 20, n = idx & 4095;
  float g1 = gp[0], g2 = gp[1];
  float sden = S[(long)b * 4096 + n] + S[8192 + (long)b * 4096 + n];
  float pamv = (O[idx] + O[2097152 + idx]) / sden;
  float v = 3.f * res[idx] + g1 * pamv + g2 * cam[idx];
  if (*flagp > 0.5f) ((float*)outp)[idx] = v;
  else               ((u16*)outp)[idx] = f2b(v);
}

// ---------------- launch ----------------

extern "C" void kernel_launch(void* const* d_in, const int* in_sizes, int n_in,
                              void* d_out, int out_size, void* d_ws, size_t ws_size,
                              hipStream_t stream)
{
  (void)out_size; (void)ws_size; (void)n_in;
  float* ws = (float*)d_ws;
  const long CN = 1048576;   // 256*4096

  float* A  = ws;            // r bf16 -> res fp32
  float* Bp = ws + 2 * CN;   // xf fp32 -> s3out/s5out/resb bf16
  float* Cp = ws + 4 * CN;   // CoordAtt smalls -> s1out bf16 -> vb bf16
  float* D  = ws + 6 * CN;   // cat(8CN u16) -> y12 -> {attn smalls} -> cam; O0/O1 at +4CN
  const long WFo = 14 * CN;

  u16*   rB   = (u16*)A;
  float* res  = A;
  float* xf   = Bp;
  u16*   BpU  = (u16*)Bp;
  float* yin  = Cp;
  float* ybn  = Cp + 65536;
  float* ah   = Cp + 67584;
  float* aw_  = Cp + 100352;
  u16*   CpU  = (u16*)Cp;
  u16*   catU = (u16*)D;
  u16*   y12U = (u16*)D;
  float* D2   = D + 2 * CN;
  u16*   qkbU = (u16*)D2;
  u16*   qkTU = (u16*)(D2 + 262144);
  float* pmax = D2 + 524288;
  float* rmx  = D2 + 557056;
  float* e    = D2 + 565248;
  u16*   attnc= (u16*)(D2 + 696320);
  float* S0   = D2 + 761856;
  float* cam  = D;
  float* O0   = D + 4 * CN;

  ConvArgs ca;
  long fOff[30], hOff[30];
  long hcur = 0;
  float* flagp = ws + WFo;
  {
    long cum = 0, fcur = WFo + 4;
    for (int i = 0; i < 30; ++i) {
      ca.src[i] = d_in[i];
      int h = (i == 8 || i == 10 || i == 14 || i == 16 || i == 20 ||
               i == 22 || i == 24 || i == 26) ? 1 : 0;
      ca.mode[i] = h;
      if (i == 0) { ca.dst[i] = 2 * CN; fOff[i] = 2 * CN; }
      else if (h) { ca.dst[i] = hcur; hOff[i] = hcur; hcur += in_sizes[i]; }
      else        { ca.dst[i] = fcur; fOff[i] = fcur; fcur += in_sizes[i]; }
      cum += in_sizes[i];
      ca.end[i] = (int)cum;
    }
  }
  long fTotal = WFo + 4;
  for (int i = 1; i < 30; ++i) if (!ca.mode[i]) fTotal = (fOff[i] + in_sizes[i] > fTotal) ? fOff[i] + in_sizes[i] : fTotal;
  u16* wsH = (u16*)(ws + fTotal);
  u16* wt3a = wsH + hcur;
  u16* wt3b = wsH + hcur + 589824;
  int total = ca.end[29];

  detect_k<<<dim3(1), dim3(128), 0, stream>>>((const u16*)d_in[0], flagp);
  convert_all<<<dim3((total + 255) / 256), dim3(256), 0, stream>>>(ca, ws, wsH, flagp, total);

  float* ca_w1 = ws + fOff[1];
  float* ca_b1 = ws + fOff[2];
  float* ca_bn = ws + fOff[3];
  float* ca_wh = ws + fOff[4];
  float* ca_bh = ws + fOff[5];
  float* ca_ww = ws + fOff[6];
  float* ca_bw = ws + fOff[7];
  u16*   s1_w  = wsH + hOff[8];   float* s1_bn = ws + fOff[9];
  u16*   s2_w  = wsH + hOff[10];  float* s2_bn = ws + fOff[11];
  float* s3_wf = ws + fOff[12];   float* s3_bn = ws + fOff[13];
  u16*   s4_w  = wsH + hOff[14];  float* s4_bn = ws + fOff[15];
  u16*   s5_w  = wsH + hOff[16];  float* s5_bn = ws + fOff[17];
  float* s6_wf = ws + fOff[18];   float* s6_bn = ws + fOff[19];
  u16*   s7_w  = wsH + hOff[20];  float* s7_bn = ws + fOff[21];
  u16*   qk_w  = wsH + hOff[22];  float* qk_b  = ws + fOff[23];
  u16*   pv_w  = wsH + hOff[26];  float* pv_b  = ws + fOff[27];
  float* gammas = ws + fOff[28];

  w3t<<<dim3(2304), dim3(256), 0, stream>>>(s3_wf, wt3a);
  w3t<<<dim3(2304), dim3(256), 0, stream>>>(s6_wf, wt3b);

  // ---- CoordAtt ----
  plane_means<<<dim3(512), dim3(256), 0, stream>>>(xf, yin);
  ca_conv1<<<dim3(2), dim3(128), 0, stream>>>(yin, ca_w1, ca_b1, ca_bn, ybn);
  ca_gate<<<dim3(256, 2), dim3(128), 0, stream>>>(ybn, ca_wh, ca_bh, ca_ww, ca_bw, ah, aw_);
  apply_ca<<<dim3(8192), dim3(256), 0, stream>>>(xf, ah, aw_, rB);

  // ---- SPPCSPC (bf16 activations) ----
  mfma_cbs<1,1><<<dim3(64, 4, 2), dim3(256), 0, stream>>>(s1_w, 0, rB, CN, CpU, CN, 256, 256, 4096, s1_bn, nullptr);
  conv3_mfma<<<dim3(32, 4, 2), dim3(256), 0, stream>>>(wt3a, CpU, CN, BpU, CN, 256, 256, s3_bn);
  mfma_cbs<1,1><<<dim3(64, 4, 2), dim3(256), 0, stream>>>(s4_w, 0, BpU, CN, catU, 4 * CN, 256, 256, 4096, s4_bn, nullptr);

  pool3<<<dim3(256, 2), dim3(256), 0, stream>>>(catU, 4 * CN);

  mfma_cbs<1,1><<<dim3(64, 4, 2), dim3(256), 0, stream>>>(s5_w, 0, catU, 4 * CN, BpU, CN, 256, 1024, 4096, s5_bn, nullptr);
  conv3_mfma<<<dim3(32, 4, 2), dim3(256), 0, stream>>>(wt3b, BpU, CN, y12U, 2 * CN, 256, 256, s6_bn);
  mfma_cbs<1,1><<<dim3(64, 4, 2), dim3(256), 0, stream>>>(s2_w, 0, rB, CN, y12U + CN, 2 * CN, 256, 256, 4096, s2_bn, nullptr);
  mfma_cbs<1,0><<<dim3(64, 4, 2), dim3(256), 0, stream>>>(s7_w, 0, y12U, 2 * CN, res, CN, 256, 512, 4096, s7_bn, nullptr);

  // ---- PAM ----
  cvtb<<<dim3(1024), dim3(256), 0, stream>>>(res, BpU, 262144);   // resb
  mfma_cbs<0,1><<<dim3(64, 1, 2), dim3(256), 0, stream>>>(qk_w, 0, BpU, CN, qkbU, 262144, 64, 256, 4096, nullptr, qk_b);
  mfma_cbs<0,1><<<dim3(64, 4, 2), dim3(256), 0, stream>>>(pv_w, 0, BpU, CN, CpU, CN, 256, 256, 4096, nullptr, pv_b);
  transpose_hh<<<dim3(128, 2, 2), dim3(256), 0, stream>>>(qkbU, qkTU);

  pam_qk_max<<<dim3(128, 4, 2), dim3(256), 0, stream>>>(qkTU, pmax);
  pam_merge<<<dim3(32), dim3(256), 0, stream>>>(pmax, rmx);
  pam_attn<<<dim3(128, 2, 2), dim3(512), 0, stream>>>(qkTU, CpU, rmx, O0, S0);

  // ---- CAM ----
  fillz<<<dim3(512), dim3(256), 0, stream>>>(e, 131072);
  cam_e_mfma<<<dim3(2, 4, 32), dim3(256), 0, stream>>>(BpU, e);
  cam_softmax<<<dim3(256, 2), dim3(256), 0, stream>>>(e, attnc);
  mfma_cbs<0,0><<<dim3(64, 4, 2), dim3(256), 0, stream>>>(attnc, 65536, BpU, CN, cam, CN, 256, 256, 4096, nullptr, nullptr);

  // ---- combine ----
  combine<<<dim3(8192), dim3(256), 0, stream>>>(res, O0, S0, cam, gammas, d_out, flagp);
}

// Round 12
// 459.601 us; speedup vs baseline: 1.2181x; 1.2181x over previous
//
#include <hip/hip_runtime.h>

typedef unsigned short u16;
typedef __attribute__((ext_vector_type(8))) short bf16x8;
typedef __attribute__((ext_vector_type(4))) float f32x4;
#define EPSV 1e-5f
#define LOG2E 1.4426950408889634f

__device__ __forceinline__ float b2f(u16 u) {
  union { float f; unsigned int i; } v; v.i = ((unsigned int)u) << 16; return v.f;
}
__device__ __forceinline__ u16 f2b(float f) {
  union { float f; unsigned int i; } v; v.f = f;
  unsigned int r = v.i + 0x7FFFu + ((v.i >> 16) & 1u);
  return (u16)(r >> 16);
}
__device__ __forceinline__ u16 f2b_trunc(float f) {
  union { float f; unsigned int i; } v; v.f = f;
  return (u16)(v.i >> 16);
}
__device__ __forceinline__ float silu_(float z) { return z / (1.f + exp2f(-LOG2E * z)); }

// ---------------- dtype detect ----------------
__global__ __launch_bounds__(128) void detect_k(const u16* __restrict__ xp, float* __restrict__ flag) {
  __shared__ int cnt[2];
  int t = threadIdx.x;
  if (t < 2) cnt[t] = 0;
  __syncthreads();
  u16 u = xp[t * 2];
  int e = (u >> 7) & 0xff;
  if (e != 0 && (e < 90 || e > 160)) atomicAdd(&cnt[0], 1);
  if (u == 0) atomicAdd(&cnt[1], 1);
  __syncthreads();
  if (t == 0) *flag = (cnt[0] > 16 || cnt[1] > 64) ? 1.f : 0.f;
}

// ---------------- input conversion ----------------

struct ConvArgs {
  const void* src[30];
  long dst[30];
  int end[30];
  int mode[30];
};

__global__ __launch_bounds__(256) void convert_all(ConvArgs a, float* __restrict__ wsF,
                                                   u16* __restrict__ wsH,
                                                   const float* __restrict__ flagp, int total) {
  const int flag = (*flagp > 0.5f);
  int gid = blockIdx.x * 256 + threadIdx.x;
  if (gid >= total) return;
  #pragma unroll 1
  for (int s = 0; s < 30; ++s) {
    if (gid < a.end[s]) {
      int idx = gid - (s ? a.end[s - 1] : 0);
      if (a.mode[s] == 0) {
        float v = flag ? ((const float*)a.src[s])[idx] : b2f(((const u16*)a.src[s])[idx]);
        wsF[a.dst[s] + idx] = v;
      } else {
        u16 h = flag ? f2b(((const float*)a.src[s])[idx]) : ((const u16*)a.src[s])[idx];
        wsH[a.dst[s] + idx] = h;
      }
      return;
    }
  }
}

// conv3 weight transform: fp32 W[o][I][3][3] -> bf16 Wt[I/32][tap][256o][32ch]
__global__ __launch_bounds__(256) void w3t(const float* __restrict__ Wsrc, u16* __restrict__ Wdst) {
  int idx = blockIdx.x * 256 + threadIdx.x;
  int ch = idx & 31;
  int o  = (idx >> 5) & 255;
  int tap = (idx >> 13) % 9;
  int c8 = (idx >> 13) / 9;
  int i = c8 * 32 + ch;
  Wdst[idx] = f2b(Wsrc[((long)o * 256 + i) * 9 + tap]);
}

// fp32 -> bf16 bulk convert (8 elems/thread)
__global__ __launch_bounds__(256) void cvtb(const float* __restrict__ src, u16* __restrict__ dst, int n8) {
  int i = blockIdx.x * 256 + threadIdx.x;
  if (i >= n8) return;
  float4 f0 = *(const float4*)(src + (long)i * 8);
  float4 f1 = *(const float4*)(src + (long)i * 8 + 4);
  union { u16 h[8]; uint4 q; } u;
  u.h[0]=f2b(f0.x); u.h[1]=f2b(f0.y); u.h[2]=f2b(f0.z); u.h[3]=f2b(f0.w);
  u.h[4]=f2b(f1.x); u.h[5]=f2b(f1.y); u.h[6]=f2b(f1.z); u.h[7]=f2b(f1.w);
  *(uint4*)(dst + (long)i * 8) = u.q;
}

// ---------------- CoordAtt ----------------

__global__ __launch_bounds__(256) void plane_means(const float* __restrict__ x, float* __restrict__ yin) {
  __shared__ float pl[4096];
  int bc = blockIdx.x, t = threadIdx.x;
  const float* xp = x + (long)bc * 4096;
  for (int j = 0; j < 16; ++j) { int id = j * 256 + t; pl[id] = xp[id]; }
  __syncthreads();
  if (t < 64) {
    float s = 0.f;
    for (int w = 0; w < 64; ++w) s += pl[t * 64 + w];
    yin[(long)bc * 128 + t] = s * (1.f / 64.f);
  } else if (t < 128) {
    int w = t - 64; float s = 0.f;
    for (int h = 0; h < 64; ++h) s += pl[h * 64 + w];
    yin[(long)bc * 128 + 64 + w] = s * (1.f / 64.f);
  }
}

__global__ __launch_bounds__(128) void ca_conv1(const float* __restrict__ yin, const float* __restrict__ w1,
                                                const float* __restrict__ b1, const float* __restrict__ bnp,
                                                float* __restrict__ ybn) {
  int b = blockIdx.x, p = threadIdx.x;
  float acc[8] = {0.f,0.f,0.f,0.f,0.f,0.f,0.f,0.f};
  for (int c = 0; c < 256; ++c) {
    float yv = yin[((long)b * 256 + c) * 128 + p];
    #pragma unroll
    for (int o = 0; o < 8; ++o) acc[o] += w1[o * 256 + c] * yv;
  }
  #pragma unroll
  for (int o = 0; o < 8; ++o) {
    float z = acc[o] + b1[o];
    float g = bnp[o], bt = bnp[8 + o], mn = bnp[16 + o], vr = bnp[24 + o];
    float s = g * rsqrtf(vr + EPSV);
    z = z * s + (bt - mn * s);
    float hs = fminf(fmaxf(z + 3.f, 0.f), 6.f) * (1.f / 6.f);
    ybn[((long)b * 8 + o) * 128 + p] = z * hs;
  }
}

__global__ __launch_bounds__(128) void ca_gate(const float* __restrict__ ybn,
    const float* __restrict__ wh, const float* __restrict__ bh,
    const float* __restrict__ ww, const float* __restrict__ bw,
    float* __restrict__ ah, float* __restrict__ aw_) {
  int c = blockIdx.x, b = blockIdx.y, t = threadIdx.x;
  if (t < 64) {
    float d = 0.f;
    #pragma unroll
    for (int o = 0; o < 8; ++o) d += wh[c * 8 + o] * ybn[((long)b * 8 + o) * 128 + t];
    d += bh[c];
    ah[((long)b * 256 + c) * 64 + t] = 1.f / (1.f + exp2f(-LOG2E * d));
  } else {
    int w = t - 64;
    float d = 0.f;
    #pragma unroll
    for (int o = 0; o < 8; ++o) d += ww[c * 8 + o] * ybn[((long)b * 8 + o) * 128 + 64 + w];
    d += bw[c];
    aw_[((long)b * 256 + c) * 64 + w] = 1.f / (1.f + exp2f(-LOG2E * d));
  }
}

// r (bf16 out) = x * a_h * a_w
__global__ __launch_bounds__(256) void apply_ca(const float* __restrict__ x, const float* __restrict__ ah,
                                                const float* __restrict__ aw_, u16* __restrict__ r) {
  int idx = blockIdx.x * 256 + threadIdx.x;
  int n = idx & 4095, bc = idx >> 12;
  int h = n >> 6, w = n & 63;
  r[idx] = f2b(x[idx] * ah[bc * 64 + h] * aw_[bc * 64 + w]);
}

// ---------------- MFMA 1x1 conv, 64o x 64n tile (2 blocks/CU): bf16 in; OUTH -> bf16/fp32 out ----------------

template<int ACT, int OUTH>
__global__ __launch_bounds__(256) void mfma_cbs(
    const u16* __restrict__ Wbf, long aBS,
    const u16* __restrict__ In, long bBS,
    void* __restrict__ Out, long oBS,
    int O, int K, int N,
    const float* __restrict__ bnp, const float* __restrict__ bias)
{
  __shared__ u16 As[64 * 40];
  __shared__ u16 Bs[64 * 40];
  __shared__ float albe[64][2];
  const int t = threadIdx.x;
  const int n0 = blockIdx.x * 64;
  const int o0 = blockIdx.y * 64;
  const int b  = blockIdx.z;
  const int w = t >> 6, l = t & 63, lq = l >> 4, lr = l & 15;
  const int wo = (w >> 1) * 32, wn = (w & 1) * 32;
  if (t < 64) {
    int o = o0 + t;
    float al = 1.f, be = 0.f;
    if (bnp) {
      float g = bnp[o], bt = bnp[O + o], mn = bnp[2 * O + o], vr = bnp[3 * O + o];
      al = g * rsqrtf(vr + EPSV); be = bt - mn * al;
    }
    if (bias) be += bias[o];
    albe[t][0] = al; albe[t][1] = be;
  }
  const u16* Ab = Wbf + (long)b * aBS;
  const u16* inb = In + (long)b * bBS + n0;
  const int ao = t >> 2, akq = (t & 3) * 8;
  const int bk = t >> 3, bn8 = (t & 7) * 8;
  f32x4 acc[2][2] = {};
  for (int kc = 0; kc < K; kc += 32) {
    __syncthreads();
    *(uint4*)&As[ao * 40 + akq] = *(const uint4*)(Ab + (long)(o0 + ao) * K + kc + akq);
    union { uint4 q; u16 h[8]; } tb;
    tb.q = *(const uint4*)(inb + (long)(kc + bk) * N + bn8);
    #pragma unroll
    for (int j = 0; j < 8; ++j) Bs[(bn8 + j) * 40 + bk] = tb.h[j];
    __syncthreads();
    bf16x8 af[2], bfv[2];
    #pragma unroll
    for (int i = 0; i < 2; ++i) af[i] = *(const bf16x8*)&As[(wo + i * 16 + lr) * 40 + lq * 8];
    #pragma unroll
    for (int j = 0; j < 2; ++j) bfv[j] = *(const bf16x8*)&Bs[(wn + j * 16 + lr) * 40 + lq * 8];
    #pragma unroll
    for (int i = 0; i < 2; ++i)
      #pragma unroll
      for (int j = 0; j < 2; ++j)
        acc[i][j] = __builtin_amdgcn_mfma_f32_16x16x32_bf16(af[i], bfv[j], acc[i][j], 0, 0, 0);
  }
  float* ob = (float*)Out + (long)b * oBS;
  u16* obh = (u16*)Out + (long)b * oBS;
  #pragma unroll
  for (int i = 0; i < 2; ++i) {
    #pragma unroll
    for (int r = 0; r < 4; ++r) {
      int ol = wo + i * 16 + lq * 4 + r;
      float al = albe[ol][0], be = albe[ol][1];
      #pragma unroll
      for (int j = 0; j < 2; ++j) {
        float vv = acc[i][j][r] * al + be;
        if (ACT) vv = silu_(vv);
        if (OUTH) obh[(long)(o0 + ol) * N + n0 + wn + j * 16 + lr] = f2b(vv);
        else      ob[(long)(o0 + ol) * N + n0 + wn + j * 16 + lr] = vv;
      }
    }
  }
}

// ---------------- MFMA 3x3 conv (implicit GEMM), bf16 in/out ----------------
__global__ __launch_bounds__(256) void conv3_mfma(
    const u16* __restrict__ Wt,
    const u16* __restrict__ In, long iBS,
    u16* __restrict__ Out, long oBS, int O, int I,
    const float* __restrict__ bnp)
{
  __shared__ u16 As[9 * 64 * 34];
  __shared__ u16 Bs[4 * 66 * 34];
  __shared__ float albe[64][2];
  const int t = threadIdx.x;
  const int h0 = blockIdx.x * 2;
  const int o0 = blockIdx.y * 64;
  const int b  = blockIdx.z;
  const int w = t >> 6, l = t & 63, lq = l >> 4, lr = l & 15;
  const int wo = (w >> 1) * 32, wn = (w & 1) * 64;
  if (t < 64) {
    int o = o0 + t;
    float g = bnp[o], bt = bnp[O + o], mn = bnp[2 * O + o], vr = bnp[3 * O + o];
    float al = g * rsqrtf(vr + EPSV);
    albe[t][0] = al; albe[t][1] = bt - mn * al;
  }
  {
    int r = t >> 6, cs = (t >> 5) & 1, ch = t & 31;
    Bs[(r * 66 + (cs ? 65 : 0)) * 34 + ch] = 0;
  }
  const u16* inb = In + (long)b * iBS;
  const int bch = t >> 3, bcg = (t & 7) * 8;
  f32x4 acc[2][4] = {};
  for (int c8 = 0; c8 < (I >> 5); ++c8) {
    __syncthreads();
    {
      const u16* wsrc = Wt + (long)c8 * 9 * 256 * 32;
      #pragma unroll
      for (int j = 0; j < 9; ++j) {
        int e = j * 2048 + t * 8;
        int tap = e >> 11, o = (e >> 5) & 63, ch0 = e & 31;
        uint4 vv = *(const uint4*)(wsrc + ((long)tap * 256 + o0 + o) * 32 + ch0);
        *(uint4*)&As[(tap * 64 + o) * 34 + ch0] = vv;
      }
    }
    {
      const u16* cbase = inb + (long)(c8 * 32 + bch) * 4096;
      #pragma unroll
      for (int r = 0; r < 4; ++r) {
        int row = h0 - 1 + r;
        union { uint4 q; u16 h[8]; } tb;
        if (row >= 0 && row < 64) {
          tb.q = *(const uint4*)(cbase + row * 64 + bcg);
        } else {
          tb.q = make_uint4(0, 0, 0, 0);
        }
        #pragma unroll
        for (int j2 = 0; j2 < 8; ++j2)
          Bs[(r * 66 + bcg + 1 + j2) * 34 + bch] = tb.h[j2];
      }
    }
    __syncthreads();
    #pragma unroll
    for (int dy = 0; dy < 3; ++dy) {
      #pragma unroll
      for (int dx = 0; dx < 3; ++dx) {
        const int tap = dy * 3 + dx;
        bf16x8 af0 = *(const bf16x8*)&As[(tap * 64 + wo + lr) * 34 + lq * 8];
        bf16x8 af1 = *(const bf16x8*)&As[(tap * 64 + wo + 16 + lr) * 34 + lq * 8];
        #pragma unroll
        for (int j = 0; j < 4; ++j) {
          int nb = wn + j * 16;
          int rowS = (nb >> 6) + dy;
          int colS = (nb & 63) + dx;
          bf16x8 bv = *(const bf16x8*)&Bs[(rowS * 66 + colS + lr) * 34 + lq * 8];
          acc[0][j] = __builtin_amdgcn_mfma_f32_16x16x32_bf16(af0, bv, acc[0][j], 0, 0, 0);
          acc[1][j] = __builtin_amdgcn_mfma_f32_16x16x32_bf16(af1, bv, acc[1][j], 0, 0, 0);
        }
      }
    }
  }
  u16* ob = Out + (long)b * oBS;
  const int n0 = h0 * 64;
  #pragma unroll
  for (int i = 0; i < 2; ++i) {
    #pragma unroll
    for (int r = 0; r < 4; ++r) {
      int ol = wo + i * 16 + lq * 4 + r;
      float al = albe[ol][0], be = albe[ol][1];
      #pragma unroll
      for (int j = 0; j < 4; ++j) {
        float vv = silu_(acc[i][j][r] * al + be);
        ob[(long)(o0 + ol) * 4096 + n0 + wn + j * 16 + lr] = f2b(vv);
      }
    }
  }
}

// ---------------- fused chained maxpools: x1 -> mp5 -> mp9 -> mp13 (bf16, in-LDS) ----------------
__global__ __launch_bounds__(256) void pool3(u16* __restrict__ cat, long bs) {
  __shared__ float A[68][72];
  __shared__ float Bb[68][72];
  const int t = threadIdx.x;
  const int c = blockIdx.x, b = blockIdx.y;
  u16* base = cat + (long)b * bs + (long)c * 4096;
  for (int i = t; i < 68 * 72; i += 256) { (&A[0][0])[i] = -1e30f; (&Bb[0][0])[i] = -1e30f; }
  __syncthreads();
  const int r = t >> 2, c0 = (t & 3) * 16;
  #pragma unroll
  for (int j = 0; j < 16; ++j) A[r + 2][c0 + 2 + j] = b2f(base[r * 64 + c0 + j]);
  const long CNu = 1048576;
  #pragma unroll 1
  for (int s = 1; s <= 3; ++s) {
    __syncthreads();
    #pragma unroll
    for (int j = 0; j < 16; ++j) {
      int cc = c0 + j;
      float m = fmaxf(fmaxf(fmaxf(A[r+2][cc], A[r+2][cc+1]), fmaxf(A[r+2][cc+2], A[r+2][cc+3])), A[r+2][cc+4]);
      Bb[r + 2][cc + 2] = m;
    }
    __syncthreads();
    u16* out = base + (long)s * CNu;
    #pragma unroll
    for (int j = 0; j < 16; ++j) {
      int hc = c0 + 2 + j;
      float m = fmaxf(fmaxf(fmaxf(Bb[r][hc], Bb[r+1][hc]), fmaxf(Bb[r+2][hc], Bb[r+3][hc])), Bb[r+4][hc]);
      out[r * 64 + c0 + j] = f2b_trunc(m);
      A[r + 2][hc] = m;
    }
  }
}

// ---------------- bf16 transpose: (B,64,4096) -> (B,4096,64) ----------------
__global__ __launch_bounds__(256) void transpose_hh(const u16* __restrict__ in, u16* __restrict__ out) {
  __shared__ u16 tile[32][34];
  int b = blockIdx.z;
  int c0 = blockIdx.x * 32, r0 = blockIdx.y * 32;
  int tx = threadIdx.x & 31, ty = threadIdx.x >> 5;
  const u16* ib = in + (long)b * 262144;
  u16* ob = out + (long)b * 262144;
  #pragma unroll
  for (int i = 0; i < 4; ++i) {
    int r = r0 + ty + i * 8;
    tile[ty + i * 8][tx] = ib[(long)r * 4096 + c0 + tx];
  }
  __syncthreads();
  #pragma unroll
  for (int i = 0; i < 4; ++i) {
    int c = c0 + ty + i * 8;
    ob[(long)c * 64 + r0 + tx] = tile[tx][ty + i * 8];
  }
}

// ---------------- PAM row-max via MFMA (qkT: [b][4096][64]) ----------------
__global__ __launch_bounds__(256) void pam_qk_max(const u16* __restrict__ qkT, float* __restrict__ pmax) {
  __shared__ u16 Qs[32 * 40];
  __shared__ u16 Ks[64 * 40];
  __shared__ float red[4][32][17];
  const int t = threadIdx.x;
  const int b = blockIdx.z, ms = blockIdx.y, n0 = blockIdx.x * 32;
  const int w = t >> 6, l = t & 63, lq = l >> 4, lr = l & 15;
  const int wn = w & 1, wc = w >> 1;
  if (t < 128) {
    int row = t >> 2, cq = (t & 3) * 8;
    *(uint4*)&Qs[row * 40 + cq] = *(const uint4*)(qkT + ((long)b * 4096 + n0 + row) * 64 + cq);
  }
  __syncthreads();
  bf16x8 qf = *(const bf16x8*)&Qs[(wn * 16 + lr) * 40 + lq * 8];
  float mx4[4] = {-1e30f, -1e30f, -1e30f, -1e30f};
  const int krow = t >> 2, kcq = (t & 3) * 8;
  for (int it = 0; it < 16; ++it) {
    int m0 = ms * 1024 + it * 64;
    __syncthreads();
    *(uint4*)&Ks[krow * 40 + kcq] = *(const uint4*)(qkT + ((long)b * 4096 + m0 + krow) * 64 + 32 + kcq);
    __syncthreads();
    #pragma unroll
    for (int s = 0; s < 2; ++s) {
      int msub = wc * 2 + s;
      bf16x8 kf = *(const bf16x8*)&Ks[(msub * 16 + lr) * 40 + lq * 8];
      f32x4 S = {};
      S = __builtin_amdgcn_mfma_f32_16x16x32_bf16(qf, kf, S, 0, 0, 0);
      #pragma unroll
      for (int r = 0; r < 4; ++r) mx4[r] = fmaxf(mx4[r], S[r]);
    }
  }
  #pragma unroll
  for (int r = 0; r < 4; ++r) red[w][wn * 16 + lq * 4 + r][lr] = mx4[r];
  __syncthreads();
  if (t < 32) {
    int wbase = t >> 4;
    float M = -1e30f;
    #pragma unroll
    for (int j = 0; j < 2; ++j)
      #pragma unroll
      for (int l2 = 0; l2 < 16; ++l2)
        M = fmaxf(M, red[wbase + 2 * j][t][l2]);
    pmax[((long)ms * 2 + b) * 4096 + n0 + t] = M;
  }
}

__global__ __launch_bounds__(256) void pam_merge(const float* __restrict__ pmax, float* __restrict__ rmx) {
  int i = blockIdx.x * 256 + threadIdx.x;
  int b = i >> 12, n = i & 4095;
  float m = pmax[(long)b * 4096 + n];
  #pragma unroll
  for (int ms = 1; ms < 4; ++ms) m = fmaxf(m, pmax[((long)ms * 2 + b) * 4096 + n]);
  rmx[i] = m;
}

// ---------------- PAM attention: m-split x2, un-normalized partials (NO prefetch) ----------------
__global__ __launch_bounds__(512) void pam_attn(const u16* __restrict__ qkT,
    const u16* __restrict__ vb, const float* __restrict__ rowmax,
    float* __restrict__ Obase, float* __restrict__ Sbase) {
  __shared__ u16 Qs[32 * 40];
  __shared__ u16 Ks[64 * 40];
  __shared__ u16 Vs[256 * 72];
  __shared__ u16 Ps[32 * 72];
  __shared__ float rmL[32];
  __shared__ float srow[32];
  const int t = threadIdx.x;
  const int mh = blockIdx.y;
  const int b = blockIdx.z;
  const int n0 = blockIdx.x * 32;
  const int w = t >> 6, l = t & 63, lq = l >> 4, lr = l & 15;
  const int nf = w & 1;
  const int mf = w >> 1;
  const int cw = w * 32;
  float* O = Obase + (long)mh * 2097152;
  float* S = Sbase + (long)mh * 8192;
  if (t < 128) {
    int row = t >> 2, cq = (t & 3) * 8;
    *(uint4*)&Qs[row * 40 + cq] = *(const uint4*)(qkT + ((long)b * 4096 + n0 + row) * 64 + cq);
  }
  if (t < 32) { rmL[t] = rowmax[(long)b * 4096 + n0 + t] * LOG2E; srow[t] = 0.f; }
  __syncthreads();
  bf16x8 qf = *(const bf16x8*)&Qs[(nf * 16 + lr) * 40 + lq * 8];
  float rm4[4];
  #pragma unroll
  for (int r = 0; r < 4; ++r) rm4[r] = rmL[nf * 16 + lq * 4 + r];
  float sp[4] = {0.f, 0.f, 0.f, 0.f};
  f32x4 acc[2][2] = {};
  const int krow = t >> 3, kc4 = (t & 7) * 4;
  const int vcc = t >> 1, vm = (t & 1) * 32;
  const u16* kbase = qkT + ((long)b * 4096 + krow) * 64 + 32 + kc4;
  const u16* vbase = vb + ((long)b * 256 + vcc) * 4096 + vm;
  const int mStart = mh * 2048, mEnd = mStart + 2048;
  for (int m0 = mStart; m0 < mEnd; m0 += 64) {
    __syncthreads();
    *(uint2*)&Ks[krow * 40 + kc4] = *(const uint2*)(kbase + (long)m0 * 64);
    {
      const u16* src = vbase + m0;
      u16* dst = &Vs[vcc * 72 + vm];
      #pragma unroll
      for (int i = 0; i < 4; ++i) *(uint4*)(dst + i * 8) = *(const uint4*)(src + i * 8);
    }
    __syncthreads();
    {
      bf16x8 kf = *(const bf16x8*)&Ks[(mf * 16 + lr) * 40 + lq * 8];
      f32x4 Sv = {};
      Sv = __builtin_amdgcn_mfma_f32_16x16x32_bf16(qf, kf, Sv, 0, 0, 0);
      #pragma unroll
      for (int r = 0; r < 4; ++r) {
        float p = exp2f(Sv[r] * LOG2E - rm4[r]);
        sp[r] += p;
        Ps[(nf * 16 + lq * 4 + r) * 72 + mf * 16 + lr] = f2b_trunc(p);
      }
    }
    __syncthreads();
    #pragma unroll
    for (int ks = 0; ks < 2; ++ks) {
      bf16x8 pf0 = *(const bf16x8*)&Ps[lr * 72 + ks * 32 + lq * 8];
      bf16x8 pf1 = *(const bf16x8*)&Ps[(16 + lr) * 72 + ks * 32 + lq * 8];
      #pragma unroll
      for (int cf = 0; cf < 2; ++cf) {
        bf16x8 vf = *(const bf16x8*)&Vs[(cw + cf * 16 + lr) * 72 + ks * 32 + lq * 8];
        acc[cf][0] = __builtin_amdgcn_mfma_f32_16x16x32_bf16(vf, pf0, acc[cf][0], 0, 0, 0);
        acc[cf][1] = __builtin_amdgcn_mfma_f32_16x16x32_bf16(vf, pf1, acc[cf][1], 0, 0, 0);
      }
    }
  }
  #pragma unroll
  for (int r = 0; r < 4; ++r) {
    float s = sp[r];
    s += __shfl_xor(s, 1); s += __shfl_xor(s, 2);
    s += __shfl_xor(s, 4); s += __shfl_xor(s, 8);
    if (lr == 0) atomicAdd(&srow[nf * 16 + lq * 4 + r], s);
  }
  __syncthreads();
  if (t < 32) S[(long)b * 4096 + n0 + t] = srow[t];
  float* ob = O + (long)b * 1048576 + n0;
  #pragma unroll
  for (int cf = 0; cf < 2; ++cf) {
    #pragma unroll
    for (int r = 0; r < 4; ++r) {
      int c = cw + cf * 16 + lq * 4 + r;
      ob[(long)c * 4096 + lr]      = acc[cf][0][r];
      ob[(long)c * 4096 + 16 + lr] = acc[cf][1][r];
    }
  }
}

// ---------------- CAM ----------------

__global__ __launch_bounds__(256) void fillz(float* __restrict__ p, int n) {
  int i = blockIdx.x * 256 + threadIdx.x;
  if (i < n) p[i] = 0.f;
}

// e[b,c,d] += sum over this block's K slice (split-K x16)
__global__ __launch_bounds__(256) void cam_e_mfma(const u16* __restrict__ resb, float* __restrict__ e) {
  __shared__ u16 As[64 * 40];
  __shared__ u16 Bs[128 * 40];
  const int t = threadIdx.x;
  const int d0 = blockIdx.x * 128;
  const int c0 = blockIdx.y * 64;
  const int bz = blockIdx.z;
  const int b = bz >> 4, ks = bz & 15;
  const int w = t >> 6, l = t & 63, lq = l >> 4, lr = l & 15;
  const int wo = (w >> 1) * 32, wn = (w & 1) * 64;
  const u16* fb = resb + (long)b * 1048576;
  const int ao = t >> 2, akq = (t & 3) * 8;
  const int bo = t >> 1, bkq = (t & 1) * 16;
  f32x4 acc[2][4] = {};
  for (int kc = ks * 256; kc < ks * 256 + 256; kc += 32) {
    __syncthreads();
    *(uint4*)&As[ao * 40 + akq] = *(const uint4*)(fb + (long)(c0 + ao) * 4096 + kc + akq);
    #pragma unroll
    for (int i = 0; i < 2; ++i)
      *(uint4*)&Bs[bo * 40 + bkq + i * 8] = *(const uint4*)(fb + (long)(d0 + bo) * 4096 + kc + bkq + i * 8);
    __syncthreads();
    bf16x8 af[2], bfv[4];
    #pragma unroll
    for (int i = 0; i < 2; ++i) af[i] = *(const bf16x8*)&As[(wo + i * 16 + lr) * 40 + lq * 8];
    #pragma unroll
    for (int j = 0; j < 4; ++j) bfv[j] = *(const bf16x8*)&Bs[(wn + j * 16 + lr) * 40 + lq * 8];
    #pragma unroll
    for (int i = 0; i < 2; ++i)
      #pragma unroll
      for (int j = 0; j < 4; ++j)
        acc[i][j] = __builtin_amdgcn_mfma_f32_16x16x32_bf16(af[i], bfv[j], acc[i][j], 0, 0, 0);
  }
  #pragma unroll
  for (int i = 0; i < 2; ++i)
    #pragma unroll
    for (int r = 0; r < 4; ++r) {
      int ol = wo + i * 16 + lq * 4 + r;
      #pragma unroll
      for (int j = 0; j < 4; ++j)
        atomicAdd(&e[((long)b << 16) + (long)(c0 + ol) * 256 + d0 + wn + j * 16 + lr], acc[i][j][r]);
    }
}

__global__ __launch_bounds__(256) void cam_softmax(const float* __restrict__ e, u16* __restrict__ attn) {
  __shared__ float red[256];
  int c = blockIdx.x, b = blockIdx.y, t = threadIdx.x;
  const float* row = e + ((long)b << 16) + (long)c * 256;
  float v = row[t];
  red[t] = v; __syncthreads();
  for (int s = 128; s > 0; s >>= 1) { if (t < s) red[t] = fminf(red[t], red[t + s]); __syncthreads(); }
  float emin = red[0]; __syncthreads();
  float ex = exp2f(LOG2E * (emin - v));
  red[t] = ex; __syncthreads();
  for (int s = 128; s > 0; s >>= 1) { if (t < s) red[t] += red[t + s]; __syncthreads(); }
  float inv = 1.f / red[0];
  attn[((long)b << 16) + (long)c * 256 + t] = f2b(ex * inv);
}

// ---------------- final combine (fuses PAM partial merge) ----------------

__global__ __launch_bounds__(256) void combine(const float* __restrict__ res, const float* __restrict__ O,
    const float* __restrict__ S, const float* __restrict__ cam, const float* __restrict__ gp,
    void* __restrict__ outp, const float* __restrict__ flagp) {
  int idx = blockIdx.x * 256 + threadIdx.x;
  int b = idx >> 20, n = idx & 4095;
  float g1 = gp[0], g2 = gp[1];
  float sden = S[(long)b * 4096 + n] + S[8192 + (long)b * 4096 + n];
  float pamv = (O[idx] + O[2097152 + idx]) / sden;
  float v = 3.f * res[idx] + g1 * pamv + g2 * cam[idx];
  if (*flagp > 0.5f) ((float*)outp)[idx] = v;
  else               ((u16*)outp)[idx] = f2b(v);
}

// ---------------- launch ----------------

extern "C" void kernel_launch(void* const* d_in, const int* in_sizes, int n_in,
                              void* d_out, int out_size, void* d_ws, size_t ws_size,
                              hipStream_t stream)
{
  (void)out_size; (void)ws_size; (void)n_in;
  float* ws = (float*)d_ws;
  const long CN = 1048576;   // 256*4096

  float* A  = ws;            // r bf16 -> res fp32
  float* Bp = ws + 2 * CN;   // xf fp32 -> s3out/s5out/resb bf16
  float* Cp = ws + 4 * CN;   // CoordAtt smalls -> s1out bf16 -> vb bf16
  float* D  = ws + 6 * CN;   // cat(8CN u16) -> y12 -> {attn smalls} -> cam; O0/O1 at +4CN
  const long WFo = 14 * CN;

  u16*   rB   = (u16*)A;
  float* res  = A;
  float* xf   = Bp;
  u16*   BpU  = (u16*)Bp;
  float* yin  = Cp;
  float* ybn  = Cp + 65536;
  float* ah   = Cp + 67584;
  float* aw_  = Cp + 100352;
  u16*   CpU  = (u16*)Cp;
  u16*   catU = (u16*)D;
  u16*   y12U = (u16*)D;
  float* D2   = D + 2 * CN;
  u16*   qkbU = (u16*)D2;
  u16*   qkTU = (u16*)(D2 + 262144);
  float* pmax = D2 + 524288;
  float* rmx  = D2 + 557056;
  float* e    = D2 + 565248;
  u16*   attnc= (u16*)(D2 + 696320);
  float* S0   = D2 + 761856;
  float* cam  = D;
  float* O0   = D + 4 * CN;

  ConvArgs ca;
  long fOff[30], hOff[30];
  long hcur = 0;
  float* flagp = ws + WFo;
  {
    long cum = 0, fcur = WFo + 4;
    for (int i = 0; i < 30; ++i) {
      ca.src[i] = d_in[i];
      int h = (i == 8 || i == 10 || i == 14 || i == 16 || i == 20 ||
               i == 22 || i == 24 || i == 26) ? 1 : 0;
      ca.mode[i] = h;
      if (i == 0) { ca.dst[i] = 2 * CN; fOff[i] = 2 * CN; }
      else if (h) { ca.dst[i] = hcur; hOff[i] = hcur; hcur += in_sizes[i]; }
      else        { ca.dst[i] = fcur; fOff[i] = fcur; fcur += in_sizes[i]; }
      cum += in_sizes[i];
      ca.end[i] = (int)cum;
    }
  }
  long fTotal = WFo + 4;
  for (int i = 1; i < 30; ++i) if (!ca.mode[i]) fTotal = (fOff[i] + in_sizes[i] > fTotal) ? fOff[i] + in_sizes[i] : fTotal;
  u16* wsH = (u16*)(ws + fTotal);
  u16* wt3a = wsH + hcur;
  u16* wt3b = wsH + hcur + 589824;
  int total = ca.end[29];

  detect_k<<<dim3(1), dim3(128), 0, stream>>>((const u16*)d_in[0], flagp);
  convert_all<<<dim3((total + 255) / 256), dim3(256), 0, stream>>>(ca, ws, wsH, flagp, total);

  float* ca_w1 = ws + fOff[1];
  float* ca_b1 = ws + fOff[2];
  float* ca_bn = ws + fOff[3];
  float* ca_wh = ws + fOff[4];
  float* ca_bh = ws + fOff[5];
  float* ca_ww = ws + fOff[6];
  float* ca_bw = ws + fOff[7];
  u16*   s1_w  = wsH + hOff[8];   float* s1_bn = ws + fOff[9];
  u16*   s2_w  = wsH + hOff[10];  float* s2_bn = ws + fOff[11];
  float* s3_wf = ws + fOff[12];   float* s3_bn = ws + fOff[13];
  u16*   s4_w  = wsH + hOff[14];  float* s4_bn = ws + fOff[15];
  u16*   s5_w  = wsH + hOff[16];  float* s5_bn = ws + fOff[17];
  float* s6_wf = ws + fOff[18];   float* s6_bn = ws + fOff[19];
  u16*   s7_w  = wsH + hOff[20];  float* s7_bn = ws + fOff[21];
  u16*   qk_w  = wsH + hOff[22];  float* qk_b  = ws + fOff[23];
  u16*   pv_w  = wsH + hOff[26];  float* pv_b  = ws + fOff[27];
  float* gammas = ws + fOff[28];

  w3t<<<dim3(2304), dim3(256), 0, stream>>>(s3_wf, wt3a);
  w3t<<<dim3(2304), dim3(256), 0, stream>>>(s6_wf, wt3b);

  // ---- CoordAtt ----
  plane_means<<<dim3(512), dim3(256), 0, stream>>>(xf, yin);
  ca_conv1<<<dim3(2), dim3(128), 0, stream>>>(yin, ca_w1, ca_b1, ca_bn, ybn);
  ca_gate<<<dim3(256, 2), dim3(128), 0, stream>>>(ybn, ca_wh, ca_bh, ca_ww, ca_bw, ah, aw_);
  apply_ca<<<dim3(8192), dim3(256), 0, stream>>>(xf, ah, aw_, rB);

  // ---- SPPCSPC (bf16 activations) ----
  mfma_cbs<1,1><<<dim3(64, 4, 2), dim3(256), 0, stream>>>(s1_w, 0, rB, CN, CpU, CN, 256, 256, 4096, s1_bn, nullptr);
  conv3_mfma<<<dim3(32, 4, 2), dim3(256), 0, stream>>>(wt3a, CpU, CN, BpU, CN, 256, 256, s3_bn);
  mfma_cbs<1,1><<<dim3(64, 4, 2), dim3(256), 0, stream>>>(s4_w, 0, BpU, CN, catU, 4 * CN, 256, 256, 4096, s4_bn, nullptr);

  pool3<<<dim3(256, 2), dim3(256), 0, stream>>>(catU, 4 * CN);

  mfma_cbs<1,1><<<dim3(64, 4, 2), dim3(256), 0, stream>>>(s5_w, 0, catU, 4 * CN, BpU, CN, 256, 1024, 4096, s5_bn, nullptr);
  conv3_mfma<<<dim3(32, 4, 2), dim3(256), 0, stream>>>(wt3b, BpU, CN, y12U, 2 * CN, 256, 256, s6_bn);
  mfma_cbs<1,1><<<dim3(64, 4, 2), dim3(256), 0, stream>>>(s2_w, 0, rB, CN, y12U + CN, 2 * CN, 256, 256, 4096, s2_bn, nullptr);
  mfma_cbs<1,0><<<dim3(64, 4, 2), dim3(256), 0, stream>>>(s7_w, 0, y12U, 2 * CN, res, CN, 256, 512, 4096, s7_bn, nullptr);

  // ---- PAM ----
  cvtb<<<dim3(1024), dim3(256), 0, stream>>>(res, BpU, 262144);   // resb
  mfma_cbs<0,1><<<dim3(64, 1, 2), dim3(256), 0, stream>>>(qk_w, 0, BpU, CN, qkbU, 262144, 64, 256, 4096, nullptr, qk_b);
  mfma_cbs<0,1><<<dim3(64, 4, 2), dim3(256), 0, stream>>>(pv_w, 0, BpU, CN, CpU, CN, 256, 256, 4096, nullptr, pv_b);
  transpose_hh<<<dim3(128, 2, 2), dim3(256), 0, stream>>>(qkbU, qkTU);

  pam_qk_max<<<dim3(128, 4, 2), dim3(256), 0, stream>>>(qkTU, pmax);
  pam_merge<<<dim3(32), dim3(256), 0, stream>>>(pmax, rmx);
  pam_attn<<<dim3(128, 2, 2), dim3(512), 0, stream>>>(qkTU, CpU, rmx, O0, S0);

  // ---- CAM ----
  fillz<<<dim3(512), dim3(256), 0, stream>>>(e, 131072);
  cam_e_mfma<<<dim3(2, 4, 32), dim3(256), 0, stream>>>(BpU, e);
  cam_softmax<<<dim3(256, 2), dim3(256), 0, stream>>>(e, attnc);
  mfma_cbs<0,0><<<dim3(64, 4, 2), dim3(256), 0, stream>>>(attnc, 65536, BpU, CN, cam, CN, 256, 256, 4096, nullptr, nullptr);

  // ---- combine ----
  combine<<<dim3(8192), dim3(256), 0, stream>>>(res, O0, S0, cam, gammas, d_out, flagp);
}